// Round 10
// baseline (558.357 us; speedup 1.0000x reference)
//
#include <hip/hip_runtime.h>
#include <math.h>

typedef __bf16 bf16x8 __attribute__((ext_vector_type(8)));
typedef float f32x4 __attribute__((ext_vector_type(4)));

#define MFMA_BF16(a,b,c) __builtin_amdgcn_mfma_f32_16x16x32_bf16((a),(b),(c),0,0,0)

static constexpr int S_LEN = 2048;
static constexpr int DM    = 2048;
static constexpr int NHEAD = 16;
static constexpr int LDH   = 128;
static constexpr int BATCH = 2;
static constexpr size_t QKV_SEG = (size_t)BATCH * NHEAD * S_LEN * LDH;  // elems per q/k/v

__device__ __forceinline__ unsigned short f2bf(float f) {
    unsigned u = __float_as_uint(f);
    u += 0x7fffu + ((u >> 16) & 1u);
    return (unsigned short)(u >> 16);
}
__device__ __forceinline__ float bf2f(unsigned short h) {
    return __uint_as_float(((unsigned)h) << 16);
}
__device__ __forceinline__ float fexp2(float x) { return exp2f(x); }

__device__ __forceinline__ void ld_lds16(const void* g, void* l) {
    __builtin_amdgcn_global_load_lds(
        (const __attribute__((address_space(1))) unsigned int*)g,
        (__attribute__((address_space(3))) unsigned int*)l, 16, 0, 0);
}

// ---------------- fused preprocessing: x->bf16 | rope tables | 4x weight transpose ----------------
__global__ void prep_all(const float* __restrict__ x, unsigned short* __restrict__ xb,
                         float* __restrict__ ct, float* __restrict__ st,
                         const float* __restrict__ W0, const float* __restrict__ W1,
                         const float* __restrict__ W2, const float* __restrict__ W3,
                         unsigned short* __restrict__ O0, unsigned short* __restrict__ O1,
                         unsigned short* __restrict__ O2, unsigned short* __restrict__ O3) {
    __shared__ unsigned short tile[32][33];
    int bid = blockIdx.x;
    int t = threadIdx.x;
    if (bid < 8192) {
        int idx = bid * 256 + t;
        float4 v = reinterpret_cast<const float4*>(x)[idx];
        unsigned lo = (unsigned)f2bf(v.x) | ((unsigned)f2bf(v.y) << 16);
        unsigned hi = (unsigned)f2bf(v.z) | ((unsigned)f2bf(v.w) << 16);
        reinterpret_cast<uint2*>(xb)[idx] = make_uint2(lo, hi);
    } else if (bid < 8704) {
        int i = t & 63;
        int s = (bid - 8192) * 4 + (t >> 6);
        float freq = (float)exp(-(double)(2 * i) / 128.0 * 9.210340371976184);
        float a = (float)s * freq;
        ct[s * 64 + i] = cosf(a);
        st[s * 64 + i] = sinf(a);
    } else {
        int wid = bid - 8704;
        int z = wid >> 12;
        int rem = wid & 4095;
        int k0 = (rem >> 6) * 32;
        int n0 = (rem & 63) * 32;
        const float* W = (z == 0) ? W0 : (z == 1) ? W1 : (z == 2) ? W2 : W3;
        unsigned short* Wt = (z == 0) ? O0 : (z == 1) ? O1 : (z == 2) ? O2 : O3;
        int ir = t >> 3, ic = (t & 7) * 4;
        float4 v = *reinterpret_cast<const float4*>(&W[(size_t)(k0 + ir) * DM + n0 + ic]);
        tile[ir][ic + 0] = f2bf(v.x);
        tile[ir][ic + 1] = f2bf(v.y);
        tile[ir][ic + 2] = f2bf(v.z);
        tile[ir][ic + 3] = f2bf(v.w);
        __syncthreads();
        unsigned lo = (unsigned)tile[ic + 0][ir] | ((unsigned)tile[ic + 1][ir] << 16);
        unsigned hi = (unsigned)tile[ic + 2][ir] | ((unsigned)tile[ic + 3][ir] << 16);
        *reinterpret_cast<uint2*>(&Wt[(size_t)(n0 + ir) * DM + k0 + ic]) = make_uint2(lo, hi);
    }
}

// ---------------- 256x128-tile out-proj GEMM: 3-ring counted vmcnt, fp32 out + bias ----------------
__global__ __launch_bounds__(256, 2) void gemm_out_v2(
    const unsigned short* __restrict__ A,
    const unsigned short* __restrict__ Bt,
    const float* __restrict__ b0,
    float* __restrict__ outp)
{
    constexpr int K  = DM;
    constexpr int NT = K / 32;
    constexpr int SLOT_B = 24576;
    __shared__ __attribute__((aligned(16))) unsigned short smem[36864];  // 72 KB

    int t = threadIdx.x, lane = t & 63, w = t >> 6;
    int i16 = lane & 15, quad = lane >> 4;
    int wc = w & 1, wr = w >> 1;

    int flat = blockIdx.y * 16 + blockIdx.x;
    int xcd = flat & 7, r8 = flat >> 3;
    int nbx = xcd * 2 + (r8 >> 4);
    int nby = r8 & 15;
    int m0 = nby * 256, n0 = nbx * 128;

    const unsigned short* ga[4];
    const unsigned short* gb[2];
    int loffA[4], loffB[2];
#pragma unroll
    for (int j = 0; j < 4; ++j) {
        int off = j * 4096 + t * 16;
        int row = off >> 6;
        int g = ((off >> 4) & 3) ^ ((row >> 1) & 3);
        ga[j] = A + (size_t)(m0 + row) * K + g * 8;
        loffA[j] = off;
    }
#pragma unroll
    for (int j = 0; j < 2; ++j) {
        int off = j * 4096 + t * 16;
        int row = off >> 6;
        int g = ((off >> 4) & 3) ^ ((row >> 1) & 3);
        gb[j] = Bt + (size_t)(n0 + row) * K + g * 8;
        loffB[j] = off;
    }

    auto stage = [&](int slot, int kt) {
        char* base = (char*)smem + slot * SLOT_B;
#pragma unroll
        for (int j = 0; j < 4; ++j)
            ld_lds16(ga[j] + kt * 32, base + loffA[j]);
#pragma unroll
        for (int j = 0; j < 2; ++j)
            ld_lds16(gb[j] + kt * 32, base + 16384 + loffB[j]);
    };

    f32x4 acc[8][4];
    const f32x4 z4 = {0.f, 0.f, 0.f, 0.f};
#pragma unroll
    for (int mi = 0; mi < 8; ++mi)
#pragma unroll
        for (int ni = 0; ni < 4; ++ni) acc[mi][ni] = z4;

    auto compute = [&](int slot) {
        const char* Ab = (const char*)smem + slot * SLOT_B;
        const char* Bb = Ab + 16384;
        bf16x8 bF[4];
#pragma unroll
        for (int ni = 0; ni < 4; ++ni) {
            int rB = wc * 64 + ni * 16 + i16;
            bF[ni] = *reinterpret_cast<const bf16x8*>(
                Bb + rB * 64 + ((quad ^ ((rB >> 1) & 3)) * 16));
        }
#pragma unroll
        for (int h = 0; h < 2; ++h) {
            bf16x8 aF[4];
#pragma unroll
            for (int mi = 0; mi < 4; ++mi) {
                int rA = wr * 128 + h * 64 + mi * 16 + i16;
                aF[mi] = *reinterpret_cast<const bf16x8*>(
                    Ab + rA * 64 + ((quad ^ ((rA >> 1) & 3)) * 16));
            }
            __builtin_amdgcn_s_setprio(1);
#pragma unroll
            for (int mi = 0; mi < 4; ++mi)
#pragma unroll
                for (int ni = 0; ni < 4; ++ni)
                    acc[h * 4 + mi][ni] = MFMA_BF16(aF[mi], bF[ni], acc[h * 4 + mi][ni]);
            __builtin_amdgcn_s_setprio(0);
        }
    };

    stage(0, 0); stage(1, 1);
    asm volatile("s_waitcnt vmcnt(6)" ::: "memory");
    __builtin_amdgcn_s_barrier();
    asm volatile("" ::: "memory");

    int cs = 0, ssl = 2;
    for (int tt = 0; tt < NT - 2; ++tt) {
        stage(ssl, tt + 2);
        compute(cs);
        asm volatile("s_waitcnt vmcnt(6)" ::: "memory");
        __builtin_amdgcn_s_barrier();
        asm volatile("" ::: "memory");
        cs  = (cs  == 2) ? 0 : cs  + 1;
        ssl = (ssl == 2) ? 0 : ssl + 1;
    }
    compute(cs);
    asm volatile("s_waitcnt vmcnt(0)" ::: "memory");
    __builtin_amdgcn_s_barrier();
    asm volatile("" ::: "memory");
    cs = (cs == 2) ? 0 : cs + 1;
    compute(cs);

#pragma unroll
    for (int mi = 0; mi < 8; ++mi)
#pragma unroll
        for (int ni = 0; ni < 4; ++ni) {
            int nn = n0 + wc * 64 + ni * 16 + i16;
            float bv = b0[nn];
#pragma unroll
            for (int r = 0; r < 4; ++r) {
                int mm = m0 + wr * 128 + mi * 16 + quad * 4 + r;
                outp[(size_t)mm * DM + nn] = acc[mi][ni][r] + bv;
            }
        }
}

// ---------------- 256x128-tile fused QKV GEMM v3: 2-slot ring, 3 blocks/CU ----------------
// r9 analysis: 768 blocks @ 2/CU = 1.5 rounds (25% capacity-time idle tail) and
// only 8 waves/CU. Shrink ring 3->2 slots (48KB LDS) -> 3 blocks/CU -> 768 = one
// EXACT round (zero tail) + 12 waves/CU. Counted vmcnt kept: per K-tile
// {compute; barrier; stage(K+2) into just-read slot; vmcnt(6); barrier}.
// Ledger: wait retires K(tt+1) (issued 1 compute phase ~1900cyc earlier >> HBM
// 900cyc); K(tt+2)'s 6 loads stay in flight. WAR safe: slot overwritten only
// after post-compute barrier (reads VGPR-retired before each wave's barrier).
// Epilogue: 48KB < 64KB tile -> two 32KB half-tile passes.
__global__ __launch_bounds__(256, 3) void gemm_qkv_v3(
    const unsigned short* __restrict__ A,
    const unsigned short* __restrict__ Bt,
    const float* __restrict__ b0, const float* __restrict__ b1,
    const float* __restrict__ b2,
    const float* __restrict__ ctab, const float* __restrict__ stab,
    unsigned short* __restrict__ outp)
{
    constexpr int K  = DM;
    constexpr int NT = K / 32;     // 64 K-tiles
    constexpr int SLOT_B = 24576;  // bytes per ring slot (A 16KB + B 8KB)
    __shared__ __attribute__((aligned(16))) unsigned short smem[24576];  // 48 KB

    int t = threadIdx.x, lane = t & 63, w = t >> 6;
    int i16 = lane & 15, quad = lane >> 4;
    int wc = w & 1, wr = w >> 1;

    int flat = blockIdx.y * 48 + blockIdx.x;
    int xcd = flat & 7, r8 = flat >> 3;          // r8 in [0,96)
    int nbx = xcd * 6 + (r8 >> 4);
    int nby = r8 & 15;
    int m0 = nby * 256, n0 = nbx * 128;

    const unsigned short* ga[4];
    const unsigned short* gb[2];
    int loffA[4], loffB[2];
#pragma unroll
    for (int j = 0; j < 4; ++j) {
        int off = j * 4096 + t * 16;              // within 16KB A tile
        int row = off >> 6;                       // 64B rows (32 bf16)
        int g = ((off >> 4) & 3) ^ ((row >> 1) & 3);
        ga[j] = A + (size_t)(m0 + row) * K + g * 8;
        loffA[j] = off;
    }
#pragma unroll
    for (int j = 0; j < 2; ++j) {
        int off = j * 4096 + t * 16;              // within 8KB B tile
        int row = off >> 6;
        int g = ((off >> 4) & 3) ^ ((row >> 1) & 3);
        gb[j] = Bt + (size_t)(n0 + row) * K + g * 8;
        loffB[j] = off;
    }

    auto stage = [&](int slot, int kt) {
        char* base = (char*)smem + slot * SLOT_B;
#pragma unroll
        for (int j = 0; j < 4; ++j)
            ld_lds16(ga[j] + kt * 32, base + loffA[j]);
#pragma unroll
        for (int j = 0; j < 2; ++j)
            ld_lds16(gb[j] + kt * 32, base + 16384 + loffB[j]);
    };

    f32x4 acc[8][4];
    const f32x4 z4 = {0.f, 0.f, 0.f, 0.f};
#pragma unroll
    for (int mi = 0; mi < 8; ++mi)
#pragma unroll
        for (int ni = 0; ni < 4; ++ni) acc[mi][ni] = z4;

    auto compute = [&](int slot) {
        const char* Ab = (const char*)smem + slot * SLOT_B;
        const char* Bb = Ab + 16384;
        bf16x8 bF[4];
#pragma unroll
        for (int ni = 0; ni < 4; ++ni) {
            int rB = wc * 64 + ni * 16 + i16;
            bF[ni] = *reinterpret_cast<const bf16x8*>(
                Bb + rB * 64 + ((quad ^ ((rB >> 1) & 3)) * 16));
        }
#pragma unroll
        for (int h = 0; h < 2; ++h) {
            bf16x8 aF[4];
#pragma unroll
            for (int mi = 0; mi < 4; ++mi) {
                int rA = wr * 128 + h * 64 + mi * 16 + i16;
                aF[mi] = *reinterpret_cast<const bf16x8*>(
                    Ab + rA * 64 + ((quad ^ ((rA >> 1) & 3)) * 16));
            }
            __builtin_amdgcn_s_setprio(1);
#pragma unroll
            for (int mi = 0; mi < 4; ++mi)
#pragma unroll
                for (int ni = 0; ni < 4; ++ni)
                    acc[h * 4 + mi][ni] = MFMA_BF16(aF[mi], bF[ni], acc[h * 4 + mi][ni]);
            __builtin_amdgcn_s_setprio(0);
        }
    };

    // prologue: K0 -> slot0, K1 -> slot1; wait K0
    stage(0, 0); stage(1, 1);
    asm volatile("s_waitcnt vmcnt(6)" ::: "memory");
    __builtin_amdgcn_s_barrier();
    asm volatile("" ::: "memory");

    for (int tt = 0; tt < NT - 2; ++tt) {
        compute(tt & 1);
        __builtin_amdgcn_s_barrier();              // all waves done reading slot tt&1
        asm volatile("" ::: "memory");
        stage(tt & 1, tt + 2);                     // overwrite with K(tt+2)
        asm volatile("s_waitcnt vmcnt(6)" ::: "memory");
        __builtin_amdgcn_s_barrier();              // K(tt+1) resident for all
        asm volatile("" ::: "memory");
    }
    compute((NT - 2) & 1);                         // K62 (slot 0)
    asm volatile("s_waitcnt vmcnt(0)" ::: "memory");
    __builtin_amdgcn_s_barrier();
    asm volatile("" ::: "memory");
    compute((NT - 1) & 1);                         // K63 (slot 1)
    __syncthreads();   // all LDS reads done; smem becomes Cs bounce

    // ---------------- epilogue: two 32KB half-tile passes (rows p*128..+127) ----------------
    unsigned short* Cs = smem;                 // 128x128 bf16 = 32KB per pass
    int which = n0 >> 11;                      // 0=q 1=k 2=v (uniform per block)
    int hh = (n0 & 2047) >> 7;                 // head
    const float* bp = (which == 0) ? b0 : ((which == 1) ? b1 : b2);
    int segn = n0 & 2047;
    int bb = m0 >> 11, s0 = m0 & 2047;

    if (which == 2) {
        unsigned short* vout = outp + 2 * QKV_SEG;
#pragma unroll
        for (int p = 0; p < 2; ++p) {
            if (wr == p) {
                // this wave's acc covers s-rows [p*128, p*128+128)
#pragma unroll
                for (int mi = 0; mi < 8; ++mi)
#pragma unroll
                    for (int ni = 0; ni < 4; ++ni) {
                        int d = wc * 64 + ni * 16 + i16;
                        float bv = bp[segn + d];
#pragma unroll
                        for (int r = 0; r < 4; ++r) {
                            int sl = mi * 16 + quad * 4 + r;      // local s in [0,128)
                            Cs[d * 128 + (((sl >> 3) ^ (d & 15)) * 8) + (sl & 7)] =
                                f2bf(acc[mi][ni][r] + bv);
                        }
                    }
            }
            __syncthreads();
#pragma unroll
            for (int it = 0; it < 8; ++it) {
                int idx = it * 256 + t;            // [0,2048)
                int d = idx >> 4, sg = idx & 15;
                uint4 v = *reinterpret_cast<const uint4*>(
                    &Cs[d * 128 + ((sg ^ (d & 15)) * 8)]);
                size_t oidx = (((size_t)(bb * NHEAD + hh)) * LDH + d) * S_LEN
                              + s0 + p * 128 + sg * 8;
                *reinterpret_cast<uint4*>(vout + oidx) = v;
            }
            __syncthreads();
        }
    } else {
        float qscale = (which == 0) ? (0.08838834764831845f * 1.4426950408889634f) : 1.0f;
        unsigned short* qout = outp + (size_t)which * QKV_SEG;
#pragma unroll
        for (int p = 0; p < 2; ++p) {
            if (wr == p) {
#pragma unroll
                for (int mi = 0; mi < 8; ++mi)
#pragma unroll
                    for (int ni = 0; ni < 4; ++ni) {
                        int nl = wc * 64 + ni * 16 + i16;
                        float bv = bp[segn + nl];
#pragma unroll
                        for (int r = 0; r < 4; ++r) {
                            int ml = mi * 16 + quad * 4 + r;      // local row in [0,128)
                            Cs[ml * 128 + nl] = f2bf(acc[mi][ni][r] + bv);
                        }
                    }
            }
            __syncthreads();
#pragma unroll
            for (int it = 0; it < 8; ++it) {
                int idx = it * 256 + t;            // [0,2048)
                int row = idx >> 4, c16 = idx & 15;
                int mm = m0 + p * 128 + row;
                int ss = mm & 2047, bb2 = mm >> 11;
                int i8 = (c16 & 7) * 8;
                const unsigned short* crow = Cs + row * 128 + i8 * 2;
                uint4 w0 = *reinterpret_cast<const uint4*>(crow);
                uint4 w1 = *reinterpret_cast<const uint4*>(crow + 8);
                unsigned pw[8] = {w0.x, w0.y, w0.z, w0.w, w1.x, w1.y, w1.z, w1.w};
                float4 cA = *reinterpret_cast<const float4*>(&ctab[ss * 64 + i8]);
                float4 cB = *reinterpret_cast<const float4*>(&ctab[ss * 64 + i8 + 4]);
                float4 sA = *reinterpret_cast<const float4*>(&stab[ss * 64 + i8]);
                float4 sB = *reinterpret_cast<const float4*>(&stab[ss * 64 + i8 + 4]);
                float cv[8] = {cA.x, cA.y, cA.z, cA.w, cB.x, cB.y, cB.z, cB.w};
                float sv[8] = {sA.x, sA.y, sA.z, sA.w, sB.x, sB.y, sB.z, sB.w};
                bool hi = (c16 >= 8);
                unsigned short ov[8];
#pragma unroll
                for (int j = 0; j < 8; ++j) {
                    float xe = bf2f((unsigned short)(pw[j] & 0xffff));
                    float xo = bf2f((unsigned short)(pw[j] >> 16));
                    float o = hi ? (xe * sv[j] + xo * cv[j]) : (xe * cv[j] - xo * sv[j]);
                    ov[j] = f2bf(o * qscale);
                }
                size_t oidx = (((size_t)(bb2 * NHEAD + hh)) * S_LEN + ss) * LDH + c16 * 8;
                *reinterpret_cast<uint4*>(qout + oidx) =
                    *reinterpret_cast<const uint4*>(ov);
            }
            __syncthreads();
        }
    }
}

// ---------------- flash attention v6: 32-key chunks -> 40KB LDS ----------------
__global__ __launch_bounds__(256, 3) void attn_kernel(
    const unsigned short* __restrict__ q,
    const unsigned short* __restrict__ k,
    const unsigned short* __restrict__ vt,
    unsigned short* __restrict__ att)
{
    __shared__ __attribute__((aligned(16))) unsigned short Ks[2][32 * 128];  // 16 KB
    __shared__ __attribute__((aligned(16))) unsigned short Vs[2][128 * 32];  // 16 KB
    __shared__ __attribute__((aligned(16))) unsigned short Ps[4][32 * 32];   //  8 KB

    int bid = blockIdx.x;
    int second = bid >> 8;
    int p = bid & 255;
    int xb = second ? (15 - (p >> 5)) : (p >> 5);
    int bh = p & 31;
    int b = bh >> 4, h = bh & (NHEAD - 1);
    int q0 = xb * 128;

    int t = threadIdx.x, w = t >> 6, lane = t & 63;
    int i16 = lane & 15, quad = lane >> 4;
    int qbase = q0 + w * 32;

    bf16x8 qf[2][4];
#pragma unroll
    for (int qs = 0; qs < 2; ++qs) {
        const unsigned short* qrow = q + ((size_t)bh * S_LEN + qbase + qs * 16 + i16) * LDH;
#pragma unroll
        for (int c = 0; c < 4; ++c)
            qf[qs][c] = *reinterpret_cast<const bf16x8*>(qrow + c * 32 + quad * 8);
    }

    const f32x4 z4 = {0.f, 0.f, 0.f, 0.f};
    f32x4 o[2][8];
#pragma unroll
    for (int qs = 0; qs < 2; ++qs)
#pragma unroll
        for (int dt = 0; dt < 8; ++dt) o[qs][dt] = z4;
    float l_i[2] = {0.f, 0.f};

    const unsigned short* kbh  = k  + (size_t)bh * S_LEN * LDH;
    const unsigned short* vtbh = vt + (size_t)bh * LDH * S_LEN;
    unsigned short* PsW = Ps[w];

    auto stage = [&](int buf, int kk0) {
#pragma unroll
        for (int j = 0; j < 2; ++j) {
            int off = j * 4096 + t * 16;                 // [0, 8192)
            int key = off >> 8;                          // 256 B per key row
            int gk = ((off >> 4) & 15) ^ (key & 15);
            ld_lds16(&kbh[(size_t)(kk0 + key) * LDH + gk * 8], (char*)Ks[buf] + off);
            int d = off >> 6;                            // 64 B per d row
            int gv = ((off >> 4) & 3) ^ (d & 3);
            ld_lds16(&vtbh[(size_t)d * S_LEN + kk0 + gv * 8], (char*)Vs[buf] + off);
        }
    };

    stage(0, q0);
    int nch = (S_LEN - q0) >> 5;
    for (int ci = 0; ci < nch; ++ci) {
        __syncthreads();   // drains this wave's vmcnt -> buf[ci&1] ready; guards buf reuse
        if (ci + 1 < nch) stage((ci + 1) & 1, q0 + (ci + 1) * 32);
        int kk0 = q0 + ci * 32;
        if (kk0 + 32 <= qbase) continue;   // wave fully masked
        const unsigned short* Kb = Ks[ci & 1];
        const unsigned short* Vb = Vs[ci & 1];

        // QK^T: A=K (m=key, 32 rows), B=Q (n=q)
        f32x4 s[2][2];
#pragma unroll
        for (int qs = 0; qs < 2; ++qs)
#pragma unroll
            for (int kn = 0; kn < 2; ++kn) s[qs][kn] = z4;
#pragma unroll
        for (int c = 0; c < 4; ++c) {
            bf16x8 kf[2];
#pragma unroll
            for (int kn = 0; kn < 2; ++kn) {
                int key = kn * 16 + i16;
                int gs = (c * 4 + quad) ^ (key & 15);
                kf[kn] = *reinterpret_cast<const bf16x8*>((const char*)Kb + key * 256 + gs * 16);
            }
            __builtin_amdgcn_s_setprio(1);
#pragma unroll
            for (int qs = 0; qs < 2; ++qs)
#pragma unroll
                for (int kn = 0; kn < 2; ++kn)
                    s[qs][kn] = MFMA_BF16(kf[kn], qf[qs][c], s[qs][kn]);
            __builtin_amdgcn_s_setprio(0);
        }

        bool diag = (kk0 == qbase);
#pragma unroll
        for (int qs = 0; qs < 2; ++qs) {
            int q_local = qs * 16 + i16;
            int qg = qbase + q_local;
#pragma unroll
            for (int kn = 0; kn < 2; ++kn) {
                int keyb = kk0 + kn * 16 + quad * 4;
                float pv[4];
                if (diag) {
#pragma unroll
                    for (int r = 0; r < 4; ++r)
                        pv[r] = (keyb + r >= qg) ? fexp2(s[qs][kn][r]) : 0.f;
                } else {
#pragma unroll
                    for (int r = 0; r < 4; ++r) pv[r] = fexp2(s[qs][kn][r]);
                }
                l_i[qs] += (pv[0] + pv[1]) + (pv[2] + pv[3]);
                unsigned lo = (unsigned)f2bf(pv[0]) | ((unsigned)f2bf(pv[1]) << 16);
                unsigned hi = (unsigned)f2bf(pv[2]) | ((unsigned)f2bf(pv[3]) << 16);
                int g = (kn * 2 + (quad >> 1)) ^ (q_local & 3);
                char* addr = (char*)PsW + q_local * 64 + g * 16 + (quad & 1) * 8;
                *reinterpret_cast<uint2*>(addr) = make_uint2(lo, hi);
            }
        }

        // PV: A=P (m=q, K=32 keys), B=Vt (n=d); Ps per-wave -> no barrier
        bf16x8 pf[2];
#pragma unroll
        for (int qs = 0; qs < 2; ++qs) {
            int q_local = qs * 16 + i16;
            int g = quad ^ (q_local & 3);
            pf[qs] = *reinterpret_cast<const bf16x8*>((const char*)PsW + q_local * 64 + g * 16);
        }
        __builtin_amdgcn_s_setprio(1);
#pragma unroll
        for (int dt = 0; dt < 8; ++dt) {
            int d = dt * 16 + i16;
            int gv = quad ^ (d & 3);
            bf16x8 vf = *reinterpret_cast<const bf16x8*>((const char*)Vb + d * 64 + gv * 16);
            o[0][dt] = MFMA_BF16(pf[0], vf, o[0][dt]);
            o[1][dt] = MFMA_BF16(pf[1], vf, o[1][dt]);
        }
        __builtin_amdgcn_s_setprio(0);
    }

#pragma unroll
    for (int qs = 0; qs < 2; ++qs) {
        float lr = l_i[qs];
        lr += __shfl_xor(lr, 16);
        lr += __shfl_xor(lr, 32);
        l_i[qs] = lr;
    }
#pragma unroll
    for (int qs = 0; qs < 2; ++qs) {
#pragma unroll
        for (int r = 0; r < 4; ++r) {
            float lv = __shfl(l_i[qs], quad * 4 + r);
            float inv = 1.0f / lv;
            int qrow = qbase + qs * 16 + quad * 4 + r;
            unsigned short* orow = att + ((size_t)b * S_LEN + qrow) * DM + h * LDH;
#pragma unroll
            for (int dt = 0; dt < 8; ++dt)
                orow[dt * 16 + i16] = f2bf(o[qs][dt][r] * inv);
        }
    }
}

// ---------------- launcher ----------------
extern "C" void kernel_launch(void* const* d_in, const int* in_sizes, int n_in,
                              void* d_out, int out_size, void* d_ws, size_t ws_size,
                              hipStream_t stream) {
    const float* x  = (const float*)d_in[0];
    const float* Wq = (const float*)d_in[2];
    const float* bq = (const float*)d_in[3];
    const float* Wk = (const float*)d_in[4];
    const float* bk = (const float*)d_in[5];
    const float* Wv = (const float*)d_in[6];
    const float* bv = (const float*)d_in[7];
    const float* Wo = (const float*)d_in[8];
    const float* bo = (const float*)d_in[9];

    char* ws = (char*)d_ws;
    unsigned short* xb  = (unsigned short*)(ws);                  // 16 MB
    unsigned short* Wqt = (unsigned short*)(ws + 16777216);       // QKV weights contiguous
    unsigned short* Wkt = (unsigned short*)(ws + 25165824);
    unsigned short* Wvt = (unsigned short*)(ws + 33554432);
    unsigned short* Wot = (unsigned short*)(ws + 41943040);
    unsigned short* qkv = (unsigned short*)(ws + 50331648);       // q | k | v^T, 16 MB each
    unsigned short* att = (unsigned short*)(ws + 100663296);
    float* ctab = (float*)(ws + 117440512);                       // 512 KB
    float* stab = (float*)(ws + 117964800);                       // 512 KB

    // fused preprocessing (convert + tables + 4x weight transpose)
    prep_all<<<25088, 256, 0, stream>>>(x, xb, ctab, stab,
                                        Wq, Wk, Wv, Wo, Wqt, Wkt, Wvt, Wot);

    // fused QKV projection + RoPE + V-transpose: M=4096, N=6144, K=2048
    gemm_qkv_v3<<<dim3(48, 16), 256, 0, stream>>>(
        xb, Wqt, bq, bk, bv, ctab, stab, qkv);

    attn_kernel<<<512, 256, 0, stream>>>(qkv, qkv + QKV_SEG, qkv + 2 * QKV_SEG, att);

    // output projection: M=4096, N=2048, K=2048, fp32 out
    gemm_out_v2<<<dim3(16, 16), 256, 0, stream>>>(att, Wot, bo, (float*)d_out);
}

// Round 11
// 382.317 us; speedup vs baseline: 1.4605x; 1.4605x over previous
//
#include <hip/hip_runtime.h>
#include <math.h>

typedef __bf16 bf16x8 __attribute__((ext_vector_type(8)));
typedef float f32x4 __attribute__((ext_vector_type(4)));

#define MFMA_BF16(a,b,c) __builtin_amdgcn_mfma_f32_16x16x32_bf16((a),(b),(c),0,0,0)

static constexpr int S_LEN = 2048;
static constexpr int DM    = 2048;
static constexpr int NHEAD = 16;
static constexpr int LDH   = 128;
static constexpr int BATCH = 2;
static constexpr size_t QKV_SEG = (size_t)BATCH * NHEAD * S_LEN * LDH;  // elems per q/k/v

__device__ __forceinline__ unsigned short f2bf(float f) {
    unsigned u = __float_as_uint(f);
    u += 0x7fffu + ((u >> 16) & 1u);
    return (unsigned short)(u >> 16);
}
__device__ __forceinline__ float bf2f(unsigned short h) {
    return __uint_as_float(((unsigned)h) << 16);
}
__device__ __forceinline__ float fexp2(float x) { return exp2f(x); }

__device__ __forceinline__ void ld_lds16(const void* g, void* l) {
    __builtin_amdgcn_global_load_lds(
        (const __attribute__((address_space(1))) unsigned int*)g,
        (__attribute__((address_space(3))) unsigned int*)l, 16, 0, 0);
}

// ---------------- fused preprocessing: x->bf16 | rope tables | 4x weight transpose ----------------
__global__ void prep_all(const float* __restrict__ x, unsigned short* __restrict__ xb,
                         float* __restrict__ ct, float* __restrict__ st,
                         const float* __restrict__ W0, const float* __restrict__ W1,
                         const float* __restrict__ W2, const float* __restrict__ W3,
                         unsigned short* __restrict__ O0, unsigned short* __restrict__ O1,
                         unsigned short* __restrict__ O2, unsigned short* __restrict__ O3) {
    __shared__ unsigned short tile[32][33];
    int bid = blockIdx.x;
    int t = threadIdx.x;
    if (bid < 8192) {
        int idx = bid * 256 + t;
        float4 v = reinterpret_cast<const float4*>(x)[idx];
        unsigned lo = (unsigned)f2bf(v.x) | ((unsigned)f2bf(v.y) << 16);
        unsigned hi = (unsigned)f2bf(v.z) | ((unsigned)f2bf(v.w) << 16);
        reinterpret_cast<uint2*>(xb)[idx] = make_uint2(lo, hi);
    } else if (bid < 8704) {
        int i = t & 63;
        int s = (bid - 8192) * 4 + (t >> 6);
        float freq = (float)exp(-(double)(2 * i) / 128.0 * 9.210340371976184);
        float a = (float)s * freq;
        ct[s * 64 + i] = cosf(a);
        st[s * 64 + i] = sinf(a);
    } else {
        int wid = bid - 8704;
        int z = wid >> 12;
        int rem = wid & 4095;
        int k0 = (rem >> 6) * 32;
        int n0 = (rem & 63) * 32;
        const float* W = (z == 0) ? W0 : (z == 1) ? W1 : (z == 2) ? W2 : W3;
        unsigned short* Wt = (z == 0) ? O0 : (z == 1) ? O1 : (z == 2) ? O2 : O3;
        int ir = t >> 3, ic = (t & 7) * 4;
        float4 v = *reinterpret_cast<const float4*>(&W[(size_t)(k0 + ir) * DM + n0 + ic]);
        tile[ir][ic + 0] = f2bf(v.x);
        tile[ir][ic + 1] = f2bf(v.y);
        tile[ir][ic + 2] = f2bf(v.z);
        tile[ir][ic + 3] = f2bf(v.w);
        __syncthreads();
        unsigned lo = (unsigned)tile[ic + 0][ir] | ((unsigned)tile[ic + 1][ir] << 16);
        unsigned hi = (unsigned)tile[ic + 2][ir] | ((unsigned)tile[ic + 3][ir] << 16);
        *reinterpret_cast<uint2*>(&Wt[(size_t)(n0 + ir) * DM + k0 + ic]) = make_uint2(lo, hi);
    }
}

// ---------------- 256x128-tile out-proj GEMM: 3-ring counted vmcnt, fp32 out + bias ----------------
__global__ __launch_bounds__(256, 2) void gemm_out_v2(
    const unsigned short* __restrict__ A,
    const unsigned short* __restrict__ Bt,
    const float* __restrict__ b0,
    float* __restrict__ outp)
{
    constexpr int K  = DM;
    constexpr int NT = K / 32;
    constexpr int SLOT_B = 24576;
    __shared__ __attribute__((aligned(16))) unsigned short smem[36864];  // 72 KB

    int t = threadIdx.x, lane = t & 63, w = t >> 6;
    int i16 = lane & 15, quad = lane >> 4;
    int wc = w & 1, wr = w >> 1;

    int flat = blockIdx.y * 16 + blockIdx.x;
    int xcd = flat & 7, r8 = flat >> 3;
    int nbx = xcd * 2 + (r8 >> 4);
    int nby = r8 & 15;
    int m0 = nby * 256, n0 = nbx * 128;

    const unsigned short* ga[4];
    const unsigned short* gb[2];
    int loffA[4], loffB[2];
#pragma unroll
    for (int j = 0; j < 4; ++j) {
        int off = j * 4096 + t * 16;
        int row = off >> 6;
        int g = ((off >> 4) & 3) ^ ((row >> 1) & 3);
        ga[j] = A + (size_t)(m0 + row) * K + g * 8;
        loffA[j] = off;
    }
#pragma unroll
    for (int j = 0; j < 2; ++j) {
        int off = j * 4096 + t * 16;
        int row = off >> 6;
        int g = ((off >> 4) & 3) ^ ((row >> 1) & 3);
        gb[j] = Bt + (size_t)(n0 + row) * K + g * 8;
        loffB[j] = off;
    }

    auto stage = [&](int slot, int kt) {
        char* base = (char*)smem + slot * SLOT_B;
#pragma unroll
        for (int j = 0; j < 4; ++j)
            ld_lds16(ga[j] + kt * 32, base + loffA[j]);
#pragma unroll
        for (int j = 0; j < 2; ++j)
            ld_lds16(gb[j] + kt * 32, base + 16384 + loffB[j]);
    };

    f32x4 acc[8][4];
    const f32x4 z4 = {0.f, 0.f, 0.f, 0.f};
#pragma unroll
    for (int mi = 0; mi < 8; ++mi)
#pragma unroll
        for (int ni = 0; ni < 4; ++ni) acc[mi][ni] = z4;

    auto compute = [&](int slot) {
        const char* Ab = (const char*)smem + slot * SLOT_B;
        const char* Bb = Ab + 16384;
        bf16x8 bF[4];
#pragma unroll
        for (int ni = 0; ni < 4; ++ni) {
            int rB = wc * 64 + ni * 16 + i16;
            bF[ni] = *reinterpret_cast<const bf16x8*>(
                Bb + rB * 64 + ((quad ^ ((rB >> 1) & 3)) * 16));
        }
#pragma unroll
        for (int h = 0; h < 2; ++h) {
            bf16x8 aF[4];
#pragma unroll
            for (int mi = 0; mi < 4; ++mi) {
                int rA = wr * 128 + h * 64 + mi * 16 + i16;
                aF[mi] = *reinterpret_cast<const bf16x8*>(
                    Ab + rA * 64 + ((quad ^ ((rA >> 1) & 3)) * 16));
            }
            __builtin_amdgcn_s_setprio(1);
#pragma unroll
            for (int mi = 0; mi < 4; ++mi)
#pragma unroll
                for (int ni = 0; ni < 4; ++ni)
                    acc[h * 4 + mi][ni] = MFMA_BF16(aF[mi], bF[ni], acc[h * 4 + mi][ni]);
            __builtin_amdgcn_s_setprio(0);
        }
    };

    stage(0, 0); stage(1, 1);
    asm volatile("s_waitcnt vmcnt(6)" ::: "memory");
    __builtin_amdgcn_s_barrier();
    asm volatile("" ::: "memory");

    int cs = 0, ssl = 2;
    for (int tt = 0; tt < NT - 2; ++tt) {
        stage(ssl, tt + 2);
        compute(cs);
        asm volatile("s_waitcnt vmcnt(6)" ::: "memory");
        __builtin_amdgcn_s_barrier();
        asm volatile("" ::: "memory");
        cs  = (cs  == 2) ? 0 : cs  + 1;
        ssl = (ssl == 2) ? 0 : ssl + 1;
    }
    compute(cs);
    asm volatile("s_waitcnt vmcnt(0)" ::: "memory");
    __builtin_amdgcn_s_barrier();
    asm volatile("" ::: "memory");
    cs = (cs == 2) ? 0 : cs + 1;
    compute(cs);

#pragma unroll
    for (int mi = 0; mi < 8; ++mi)
#pragma unroll
        for (int ni = 0; ni < 4; ++ni) {
            int nn = n0 + wc * 64 + ni * 16 + i16;
            float bv = b0[nn];
#pragma unroll
            for (int r = 0; r < 4; ++r) {
                int mm = m0 + wr * 128 + mi * 16 + quad * 4 + r;
                outp[(size_t)mm * DM + nn] = acc[mi][ni][r] + bv;
            }
        }
}

// ---------------- 256x128-tile fused QKV GEMM: 3-deep ring, counted vmcnt ----------------
// REVERT of v3 (2-slot ring @ launch_bounds(256,3)): that bound caps the
// allocator at ~170 unified VGPRs but the kernel needs ~224 (128 acc + ~96
// arch) -> acc spilled to scratch -> WRITE_SIZE 49->345 MB, qkv 120->287 us.
// Occupancy here is VGPR-bound at 2 waves/SIMD; LDS shrinking cannot help.
__global__ __launch_bounds__(256, 2) void gemm_qkv_v2(
    const unsigned short* __restrict__ A,
    const unsigned short* __restrict__ Bt,
    const float* __restrict__ b0, const float* __restrict__ b1,
    const float* __restrict__ b2,
    const float* __restrict__ ctab, const float* __restrict__ stab,
    unsigned short* __restrict__ outp)
{
    constexpr int K  = DM;
    constexpr int NT = K / 32;     // 64 K-tiles
    constexpr int SLOT_B = 24576;  // bytes per ring slot (A 16KB + B 8KB)
    __shared__ __attribute__((aligned(16))) unsigned short smem[36864];  // 72 KB

    int t = threadIdx.x, lane = t & 63, w = t >> 6;
    int i16 = lane & 15, quad = lane >> 4;
    int wc = w & 1, wr = w >> 1;

    int flat = blockIdx.y * 48 + blockIdx.x;
    int xcd = flat & 7, r8 = flat >> 3;          // r8 in [0,96)
    int nbx = xcd * 6 + (r8 >> 4);
    int nby = r8 & 15;
    int m0 = nby * 256, n0 = nbx * 128;

    const unsigned short* ga[4];
    const unsigned short* gb[2];
    int loffA[4], loffB[2];
#pragma unroll
    for (int j = 0; j < 4; ++j) {
        int off = j * 4096 + t * 16;              // within 16KB A tile
        int row = off >> 6;                       // 64B rows (32 bf16)
        int g = ((off >> 4) & 3) ^ ((row >> 1) & 3);
        ga[j] = A + (size_t)(m0 + row) * K + g * 8;
        loffA[j] = off;
    }
#pragma unroll
    for (int j = 0; j < 2; ++j) {
        int off = j * 4096 + t * 16;              // within 8KB B tile
        int row = off >> 6;
        int g = ((off >> 4) & 3) ^ ((row >> 1) & 3);
        gb[j] = Bt + (size_t)(n0 + row) * K + g * 8;
        loffB[j] = off;
    }

    auto stage = [&](int slot, int kt) {
        char* base = (char*)smem + slot * SLOT_B;
#pragma unroll
        for (int j = 0; j < 4; ++j)
            ld_lds16(ga[j] + kt * 32, base + loffA[j]);
#pragma unroll
        for (int j = 0; j < 2; ++j)
            ld_lds16(gb[j] + kt * 32, base + 16384 + loffB[j]);
    };

    f32x4 acc[8][4];
    const f32x4 z4 = {0.f, 0.f, 0.f, 0.f};
#pragma unroll
    for (int mi = 0; mi < 8; ++mi)
#pragma unroll
        for (int ni = 0; ni < 4; ++ni) acc[mi][ni] = z4;

    auto compute = [&](int slot) {
        const char* Ab = (const char*)smem + slot * SLOT_B;
        const char* Bb = Ab + 16384;
        bf16x8 bF[4];
#pragma unroll
        for (int ni = 0; ni < 4; ++ni) {
            int rB = wc * 64 + ni * 16 + i16;
            bF[ni] = *reinterpret_cast<const bf16x8*>(
                Bb + rB * 64 + ((quad ^ ((rB >> 1) & 3)) * 16));
        }
#pragma unroll
        for (int h = 0; h < 2; ++h) {
            bf16x8 aF[4];
#pragma unroll
            for (int mi = 0; mi < 4; ++mi) {
                int rA = wr * 128 + h * 64 + mi * 16 + i16;
                aF[mi] = *reinterpret_cast<const bf16x8*>(
                    Ab + rA * 64 + ((quad ^ ((rA >> 1) & 3)) * 16));
            }
            __builtin_amdgcn_s_setprio(1);
#pragma unroll
            for (int mi = 0; mi < 4; ++mi)
#pragma unroll
                for (int ni = 0; ni < 4; ++ni)
                    acc[h * 4 + mi][ni] = MFMA_BF16(aF[mi], bF[ni], acc[h * 4 + mi][ni]);
            __builtin_amdgcn_s_setprio(0);
        }
    };

    stage(0, 0); stage(1, 1);
    asm volatile("s_waitcnt vmcnt(6)" ::: "memory");
    __builtin_amdgcn_s_barrier();
    asm volatile("" ::: "memory");

    int cs = 0, ssl = 2;
    for (int tt = 0; tt < NT - 2; ++tt) {
        stage(ssl, tt + 2);
        compute(cs);
        asm volatile("s_waitcnt vmcnt(6)" ::: "memory");
        __builtin_amdgcn_s_barrier();
        asm volatile("" ::: "memory");
        cs  = (cs  == 2) ? 0 : cs  + 1;
        ssl = (ssl == 2) ? 0 : ssl + 1;
    }
    compute(cs);                               // K-tile NT-2
    asm volatile("s_waitcnt vmcnt(0)" ::: "memory");
    __builtin_amdgcn_s_barrier();
    asm volatile("" ::: "memory");
    cs = (cs == 2) ? 0 : cs + 1;
    compute(cs);                               // K-tile NT-1
    __syncthreads();   // all LDS reads done; ring becomes Cs bounce

    // ---------------- epilogue (one head per block: BN=128) ----------------
    unsigned short* Cs = smem;                 // 256x128 bf16 = 64KB (of 72KB)
    int which = n0 >> 11;                      // 0=q 1=k 2=v (uniform per block)
    int hh = (n0 & 2047) >> 7;                 // head
    const float* bp = (which == 0) ? b0 : ((which == 1) ? b1 : b2);
    int segn = n0 & 2047;
    int bb = m0 >> 11, s0 = m0 & 2047;

    if (which == 2) {
#pragma unroll
        for (int mi = 0; mi < 8; ++mi)
#pragma unroll
            for (int ni = 0; ni < 4; ++ni) {
                int d = wc * 64 + ni * 16 + i16;
                float bv = bp[segn + d];
#pragma unroll
                for (int r = 0; r < 4; ++r) {
                    int sl = wr * 128 + mi * 16 + quad * 4 + r;
                    Cs[d * 256 + (((sl >> 3) ^ (d & 31)) * 8) + (sl & 7)] =
                        f2bf(acc[mi][ni][r] + bv);
                }
            }
        __syncthreads();
        unsigned short* vout = outp + 2 * QKV_SEG;
#pragma unroll
        for (int it = 0; it < 16; ++it) {
            int idx = it * 256 + t;
            int d = idx >> 5, sg = idx & 31;
            uint4 v = *reinterpret_cast<const uint4*>(
                &Cs[d * 256 + ((sg ^ (d & 31)) * 8)]);
            size_t oidx = (((size_t)(bb * NHEAD + hh)) * LDH + d) * S_LEN + s0 + sg * 8;
            *reinterpret_cast<uint4*>(vout + oidx) = v;
        }
    } else {
#pragma unroll
        for (int mi = 0; mi < 8; ++mi)
#pragma unroll
            for (int ni = 0; ni < 4; ++ni) {
                int nl = wc * 64 + ni * 16 + i16;
                float bv = bp[segn + nl];
#pragma unroll
                for (int r = 0; r < 4; ++r) {
                    int ml = wr * 128 + mi * 16 + quad * 4 + r;
                    Cs[ml * 128 + nl] = f2bf(acc[mi][ni][r] + bv);
                }
            }
        __syncthreads();
        float qscale = (which == 0) ? (0.08838834764831845f * 1.4426950408889634f) : 1.0f;
        unsigned short* qout = outp + (size_t)which * QKV_SEG;
#pragma unroll
        for (int it = 0; it < 16; ++it) {
            int idx = it * 256 + t;
            int row = idx >> 4, c16 = idx & 15;
            int mm = m0 + row;
            int ss = mm & 2047, bb2 = mm >> 11;
            int i8 = (c16 & 7) * 8;
            const unsigned short* crow = Cs + row * 128 + i8 * 2;
            uint4 w0 = *reinterpret_cast<const uint4*>(crow);
            uint4 w1 = *reinterpret_cast<const uint4*>(crow + 8);
            unsigned pw[8] = {w0.x, w0.y, w0.z, w0.w, w1.x, w1.y, w1.z, w1.w};
            float4 cA = *reinterpret_cast<const float4*>(&ctab[ss * 64 + i8]);
            float4 cB = *reinterpret_cast<const float4*>(&ctab[ss * 64 + i8 + 4]);
            float4 sA = *reinterpret_cast<const float4*>(&stab[ss * 64 + i8]);
            float4 sB = *reinterpret_cast<const float4*>(&stab[ss * 64 + i8 + 4]);
            float cv[8] = {cA.x, cA.y, cA.z, cA.w, cB.x, cB.y, cB.z, cB.w};
            float sv[8] = {sA.x, sA.y, sA.z, sA.w, sB.x, sB.y, sB.z, sB.w};
            bool hi = (c16 >= 8);
            unsigned short ov[8];
#pragma unroll
            for (int j = 0; j < 8; ++j) {
                float xe = bf2f((unsigned short)(pw[j] & 0xffff));
                float xo = bf2f((unsigned short)(pw[j] >> 16));
                float o = hi ? (xe * sv[j] + xo * cv[j]) : (xe * cv[j] - xo * sv[j]);
                ov[j] = f2bf(o * qscale);
            }
            size_t oidx = (((size_t)(bb2 * NHEAD + hh)) * S_LEN + ss) * LDH + c16 * 8;
            *reinterpret_cast<uint4*>(qout + oidx) =
                *reinterpret_cast<const uint4*>(ov);
        }
    }
}

// ---------------- flash attention v4: double-buffered staging + setprio ----------------
__global__ __launch_bounds__(256, 2) void attn_kernel(
    const unsigned short* __restrict__ q,
    const unsigned short* __restrict__ k,
    const unsigned short* __restrict__ vt,
    unsigned short* __restrict__ att)
{
    __shared__ __attribute__((aligned(16))) unsigned short Ks[2][64 * 128];
    __shared__ __attribute__((aligned(16))) unsigned short Vs[2][128 * 64];
    __shared__ __attribute__((aligned(16))) unsigned short Ps[4][32 * 64];

    int bid = blockIdx.x;
    int second = bid >> 8;
    int p = bid & 255;
    int xb = second ? (15 - (p >> 5)) : (p >> 5);
    int bh = p & 31;
    int b = bh >> 4, h = bh & (NHEAD - 1);
    int q0 = xb * 128;

    int t = threadIdx.x, w = t >> 6, lane = t & 63;
    int i16 = lane & 15, quad = lane >> 4;
    int qbase = q0 + w * 32;

    bf16x8 qf[2][4];
#pragma unroll
    for (int qs = 0; qs < 2; ++qs) {
        const unsigned short* qrow = q + ((size_t)bh * S_LEN + qbase + qs * 16 + i16) * LDH;
#pragma unroll
        for (int c = 0; c < 4; ++c)
            qf[qs][c] = *reinterpret_cast<const bf16x8*>(qrow + c * 32 + quad * 8);
    }

    const f32x4 z4 = {0.f, 0.f, 0.f, 0.f};
    f32x4 o[2][8];
#pragma unroll
    for (int qs = 0; qs < 2; ++qs)
#pragma unroll
        for (int dt = 0; dt < 8; ++dt) o[qs][dt] = z4;
    float l_i[2] = {0.f, 0.f};

    const unsigned short* kbh  = k  + (size_t)bh * S_LEN * LDH;
    const unsigned short* vtbh = vt + (size_t)bh * LDH * S_LEN;
    unsigned short* PsW = Ps[w];

    auto stage = [&](int buf, int kk0) {
#pragma unroll
        for (int j = 0; j < 4; ++j) {
            int off = j * 4096 + w * 1024 + lane * 16;
            int key = off >> 8;
            int gk = ((off >> 4) & 15) ^ (key & 15);
            ld_lds16(&kbh[(size_t)(kk0 + key) * LDH + gk * 8], (char*)Ks[buf] + off);
            int d = off >> 7;
            int gv = ((off >> 4) & 7) ^ (d & 7);
            ld_lds16(&vtbh[(size_t)d * S_LEN + kk0 + gv * 8], (char*)Vs[buf] + off);
        }
    };

    stage(0, q0);
    int nch = (S_LEN - q0) >> 6;
    for (int ci = 0; ci < nch; ++ci) {
        __syncthreads();   // drains this wave's vmcnt -> buf[ci&1] ready; guards buf reuse
        if (ci + 1 < nch) stage((ci + 1) & 1, q0 + (ci + 1) * 64);
        int kk0 = q0 + ci * 64;
        if (kk0 + 64 <= qbase) continue;   // wave fully masked
        const unsigned short* Kb = Ks[ci & 1];
        const unsigned short* Vb = Vs[ci & 1];

        // QK^T: A=K (m=key), B=Q (n=q)
        f32x4 s[2][4];
#pragma unroll
        for (int qs = 0; qs < 2; ++qs)
#pragma unroll
            for (int kn = 0; kn < 4; ++kn) s[qs][kn] = z4;
#pragma unroll
        for (int c = 0; c < 4; ++c) {
            bf16x8 kf[4];
#pragma unroll
            for (int kn = 0; kn < 4; ++kn) {
                int key = kn * 16 + i16;
                int gs = (c * 4 + quad) ^ (key & 15);
                kf[kn] = *reinterpret_cast<const bf16x8*>((const char*)Kb + key * 256 + gs * 16);
            }
            __builtin_amdgcn_s_setprio(1);
#pragma unroll
            for (int qs = 0; qs < 2; ++qs)
#pragma unroll
                for (int kn = 0; kn < 4; ++kn)
                    s[qs][kn] = MFMA_BF16(kf[kn], qf[qs][c], s[qs][kn]);
            __builtin_amdgcn_s_setprio(0);
        }

        bool diag = (kk0 < qbase + 32);
#pragma unroll
        for (int qs = 0; qs < 2; ++qs) {
            int q_local = qs * 16 + i16;
            int qg = qbase + q_local;
#pragma unroll
            for (int kn = 0; kn < 4; ++kn) {
                int keyb = kk0 + kn * 16 + quad * 4;
                float pv[4];
                if (diag) {
#pragma unroll
                    for (int r = 0; r < 4; ++r)
                        pv[r] = (keyb + r >= qg) ? fexp2(s[qs][kn][r]) : 0.f;
                } else {
#pragma unroll
                    for (int r = 0; r < 4; ++r) pv[r] = fexp2(s[qs][kn][r]);
                }
                l_i[qs] += (pv[0] + pv[1]) + (pv[2] + pv[3]);
                unsigned lo = (unsigned)f2bf(pv[0]) | ((unsigned)f2bf(pv[1]) << 16);
                unsigned hi = (unsigned)f2bf(pv[2]) | ((unsigned)f2bf(pv[3]) << 16);
                int g = (kn * 2 + (quad >> 1)) ^ (q_local & 7);
                char* addr = (char*)PsW + q_local * 128 + g * 16 + (quad & 1) * 8;
                *reinterpret_cast<uint2*>(addr) = make_uint2(lo, hi);
            }
        }

        // PV: A=P (m=q), B=Vt (n=d); Ps per-wave -> no barrier
#pragma unroll
        for (int hh = 0; hh < 2; ++hh) {
            bf16x8 pf[2];
#pragma unroll
            for (int qs = 0; qs < 2; ++qs) {
                int q_local = qs * 16 + i16;
                int g = (hh * 4 + quad) ^ (q_local & 7);
                pf[qs] = *reinterpret_cast<const bf16x8*>((const char*)PsW + q_local * 128 + g * 16);
            }
            __builtin_amdgcn_s_setprio(1);
#pragma unroll
            for (int dt = 0; dt < 8; ++dt) {
                int d = dt * 16 + i16;
                int gv = (hh * 4 + quad) ^ (d & 7);
                bf16x8 vf = *reinterpret_cast<const bf16x8*>((const char*)Vb + d * 128 + gv * 16);
                o[0][dt] = MFMA_BF16(pf[0], vf, o[0][dt]);
                o[1][dt] = MFMA_BF16(pf[1], vf, o[1][dt]);
            }
            __builtin_amdgcn_s_setprio(0);
        }
    }

#pragma unroll
    for (int qs = 0; qs < 2; ++qs) {
        float lr = l_i[qs];
        lr += __shfl_xor(lr, 16);
        lr += __shfl_xor(lr, 32);
        l_i[qs] = lr;
    }
#pragma unroll
    for (int qs = 0; qs < 2; ++qs) {
#pragma unroll
        for (int r = 0; r < 4; ++r) {
            float lv = __shfl(l_i[qs], quad * 4 + r);
            float inv = 1.0f / lv;
            int qrow = qbase + qs * 16 + quad * 4 + r;
            unsigned short* orow = att + ((size_t)b * S_LEN + qrow) * DM + h * LDH;
#pragma unroll
            for (int dt = 0; dt < 8; ++dt)
                orow[dt * 16 + i16] = f2bf(o[qs][dt][r] * inv);
        }
    }
}

// ---------------- launcher ----------------
extern "C" void kernel_launch(void* const* d_in, const int* in_sizes, int n_in,
                              void* d_out, int out_size, void* d_ws, size_t ws_size,
                              hipStream_t stream) {
    const float* x  = (const float*)d_in[0];
    const float* Wq = (const float*)d_in[2];
    const float* bq = (const float*)d_in[3];
    const float* Wk = (const float*)d_in[4];
    const float* bk = (const float*)d_in[5];
    const float* Wv = (const float*)d_in[6];
    const float* bv = (const float*)d_in[7];
    const float* Wo = (const float*)d_in[8];
    const float* bo = (const float*)d_in[9];

    char* ws = (char*)d_ws;
    unsigned short* xb  = (unsigned short*)(ws);                  // 16 MB
    unsigned short* Wqt = (unsigned short*)(ws + 16777216);       // QKV weights contiguous
    unsigned short* Wkt = (unsigned short*)(ws + 25165824);
    unsigned short* Wvt = (unsigned short*)(ws + 33554432);
    unsigned short* Wot = (unsigned short*)(ws + 41943040);
    unsigned short* qkv = (unsigned short*)(ws + 50331648);       // q | k | v^T, 16 MB each
    unsigned short* att = (unsigned short*)(ws + 100663296);
    float* ctab = (float*)(ws + 117440512);                       // 512 KB
    float* stab = (float*)(ws + 117964800);                       // 512 KB

    // fused preprocessing (convert + tables + 4x weight transpose)
    prep_all<<<25088, 256, 0, stream>>>(x, xb, ctab, stab,
                                        Wq, Wk, Wv, Wo, Wqt, Wkt, Wvt, Wot);

    // fused QKV projection + RoPE + V-transpose: M=4096, N=6144, K=2048
    gemm_qkv_v2<<<dim3(48, 16), 256, 0, stream>>>(
        xb, Wqt, bq, bk, bv, ctab, stab, qkv);

    attn_kernel<<<512, 256, 0, stream>>>(qkv, qkv + QKV_SEG, qkv + 2 * QKV_SEG, att);

    // output projection: M=4096, N=2048, K=2048, fp32 out
    gemm_out_v2<<<dim3(16, 16), 256, 0, stream>>>(att, Wot, bo, (float*)d_out);
}